// Round 2
// baseline (105.311 us; speedup 1.0000x reference)
//
#include <hip/hip_runtime.h>
#include <stdint.h>

#define NROWS 384
#define DDIM  768
#define NCOL  1536
#define L2E2  2.885390081777927f   // 2*log2(e): exp(2s) = exp2(L2E2*s)

// ws regions (float-slot offsets):
//   EA   [384 i][768 d]  fp32 at 0        (exp2(L2E2*(A+b1)), row-major)
//   EBt  [192 dg][384 j][4] fp32 at 294912 (exp2(L2E2*B), d-blocked)
//   pbf  [384 i][768 k]  bf16 at 589824   (p converted once)
//   wbf  [768 o][1536 c] bf16 at 737280   (W1 converted once)
#define WS_BT  294912
#define WS_PBF 589824
#define WS_WBF 737280

typedef short bf16x8 __attribute__((ext_vector_type(8)));
typedef float f32x4  __attribute__((ext_vector_type(4)));

__device__ __forceinline__ uint16_t f2bf(float x) {  // RNE float->bf16
  const uint32_t u = __float_as_uint(x);
  return (uint16_t)((u + 0x7FFFu + ((u >> 16) & 1u)) >> 16);
}
__device__ __forceinline__ bf16x8 pack8(const float* f) {
  bf16x8 r;
  #pragma unroll
  for (int j = 0; j < 8; ++j) r[j] = (short)f2bf(f[j]);
  return r;
}

// ---------------------------------------------------------------------------
// K0: one-time fp32->bf16 conversion of p and W1 (layouts preserved).
// ---------------------------------------------------------------------------
__global__ __launch_bounds__(256) void k0_cvt(
    const float* __restrict__ p, const float* __restrict__ W1,
    float* __restrict__ ws) {
  const int t = blockIdx.x * 256 + threadIdx.x;
  const int NP = NROWS * DDIM / 8;          // 36864 p-tasks
  float f[8];
  if (t < NP) {
    *(float4*)&f[0] = *(const float4*)&p[t * 8];
    *(float4*)&f[4] = *(const float4*)&p[t * 8 + 4];
    *(bf16x8*)((uint16_t*)(ws + WS_PBF) + (size_t)t * 8) = pack8(f);
  } else {
    const int u = t - NP;                   // 147456 W1-tasks
    *(float4*)&f[0] = *(const float4*)&W1[(size_t)u * 8];
    *(float4*)&f[4] = *(const float4*)&W1[(size_t)u * 8 + 4];
    *(bf16x8*)((uint16_t*)(ws + WS_WBF) + (size_t)u * 8) = pack8(f);
  }
}

// ---------------------------------------------------------------------------
// K1: C[i][o] = sum_k p[i][k] * W1[o%768][(o>=768)*768 + k], MFMA bf16.
// bf16 fragments loaded directly (16B, L2-resident) — no pack VALU.
// Block = 256 thr = 4 waves = 2 n-subtiles x 2 k-halves (LDS combine).
// Grid 48x24 = 1152 blocks. Epilogue folds b1 + L2E2 AND the exp2:
// stores EA = exp2(L2E2*(A+b1)) row-major, EB = exp2(L2E2*B) d-blocked,
// so K2's inner loop needs no transcendental exp (exp(2s)=EA*EB).
// ---------------------------------------------------------------------------
__global__ __launch_bounds__(256) void k1_mfma(
    const float* __restrict__ b1, float* __restrict__ ws) {
  __shared__ float cmb[2][64][4];

  const int lane = threadIdx.x & 63;
  const int w    = threadIdx.x >> 6;
  const int nsub = w & 1;
  const int ksub = w >> 1;
  const int nn   = lane & 15;
  const int quad = lane >> 4;

  const int mbase = blockIdx.y * 16;
  const int nbase = blockIdx.x * 32 + nsub * 16;   // [0,1536)
  const int g     = nbase >= DDIM;
  const int obase = nbase - g * DDIM;              // W1 row base [0,768)

  const uint16_t* __restrict__ pa =
      (const uint16_t*)(ws + WS_PBF) + (size_t)(mbase + nn) * DDIM + ksub * 384 + quad * 8;
  const uint16_t* __restrict__ pb =
      (const uint16_t*)(ws + WS_WBF) + (size_t)(obase + nn) * NCOL + g * DDIM + ksub * 384 + quad * 8;

  f32x4 acc = {0.f, 0.f, 0.f, 0.f};

  #pragma unroll 4
  for (int kk = 0; kk < 384; kk += 32) {
    const bf16x8 a = *(const bf16x8*)&pa[kk];
    const bf16x8 b = *(const bf16x8*)&pb[kk];
    acc = __builtin_amdgcn_mfma_f32_16x16x32_bf16(a, b, acc, 0, 0, 0);
  }

  if (ksub == 1)
    *(float4*)&cmb[nsub][lane][0] = make_float4(acc[0], acc[1], acc[2], acc[3]);
  __syncthreads();
  if (ksub == 0) {
    const float4 o4 = *(const float4*)&cmb[nsub][lane][0];
    float v[4] = {acc[0] + o4.x, acc[1] + o4.y, acc[2] + o4.z, acc[3] + o4.w};
    const int od = obase + nn;
    if (!g) {
      const float bias = b1[od];
      float* __restrict__ A2 = ws;
      #pragma unroll
      for (int r = 0; r < 4; ++r)
        A2[(size_t)(mbase + quad * 4 + r) * DDIM + od] =
            __builtin_amdgcn_exp2f((v[r] + bias) * L2E2);
    } else {
      float* __restrict__ Bt = ws + WS_BT;
      const int hi = (od >> 2) * NROWS;
      const int lo = od & 3;
      #pragma unroll
      for (int r = 0; r < 4; ++r)
        Bt[(size_t)(hi + mbase + quad * 4 + r) * 4 + lo] =
            __builtin_amdgcn_exp2f(v[r] * L2E2);
    }
  }
}

// ---------------------------------------------------------------------------
// K2: logits[i][j][c] = (sumW_c - 2*sum_d W2[c][d]*r_ijd) + b2[c],
//     r = rcp(EA[i][d]*EB[j][d] + 1)   (exponentials precomputed in K1:
//     exp(2s) = EA*EB — no transcendental exp in the hot loop, only rcp).
// CHANGE vs round 1: 4 i-rows per block (grid 96x6, was 192x6). Waves =
// (row-pair rp) x (d-half h2); each wave runs the same 8-rcp/24-fma body
// over 96 dgs (was 48). The two rp-waves sharing a d-half read identical
// EB addresses in near-lockstep -> L1 dedup, so unique EB L2 traffic
// halves: 226 MB -> 113 MB. 2-way combine via 2 KB LDS (was 3-way).
// EA-row / W2 streams stay wave-uniform scalar (SMEM) loads.
// Occupancy 2.25 blocks/CU (9 waves/CU); unroll-4 keeps >=4 EB loads in
// flight per wave to cover L2 latency.
// ---------------------------------------------------------------------------
__global__ __launch_bounds__(256) void k2_fused(
    const float* __restrict__ ws, const float* __restrict__ W2,
    const float* __restrict__ b2, float* __restrict__ out) {
  __shared__ float part[2][2][64][2];   // [rp][row-in-pair][lane][c]

  const int lane = threadIdx.x & 63;
  const int wu   = __builtin_amdgcn_readfirstlane(threadIdx.x >> 6);
  const int rp   = wu & 1;              // row-pair: rows i0+2rp, i0+2rp+1
  const int h2   = wu >> 1;             // d-half 0..1
  const int i0   = blockIdx.x * 4;
  const int j    = blockIdx.y * 64 + lane;

  // Wave-uniform scalar streams for this row-pair / d-half.
  const int ia = i0 + rp * 2;
  const float* __restrict__ ea0 = ws + (size_t)ia * DDIM + h2 * 384;
  const float* __restrict__ ea1 = ea0 + DDIM;
  const float* __restrict__ w2a = W2 + h2 * 384;
  const float* __restrict__ w2b = w2a + DDIM;

  // half-range sumW (wave-uniform after butterfly)
  float sw0 = 0.f, sw1 = 0.f;
  #pragma unroll
  for (int u = 0; u < 6; ++u) {
    sw0 += w2a[lane + 64 * u];
    sw1 += w2b[lane + 64 * u];
  }
  #pragma unroll
  for (int off = 32; off; off >>= 1) {
    sw0 += __shfl_xor(sw0, off);
    sw1 += __shfl_xor(sw1, off);
  }

  const float4* __restrict__ B4 =
      (const float4*)(ws + WS_BT) + (size_t)(h2 * 96) * NROWS + j;

  f32x4 s00 = {0,0,0,0}, s01 = {0,0,0,0};   // row ia+0: c0, c1
  f32x4 s10 = {0,0,0,0}, s11 = {0,0,0,0};   // row ia+1: c0, c1

  #pragma unroll 4
  for (int dg = 0; dg < 96; ++dg) {
    const float4 b4  = B4[(size_t)dg * NROWS];          // coalesced per-lane (EB)
    const float4 av0 = *(const float4*)&ea0[dg * 4];    // wave-uniform (SMEM)
    const float4 av1 = *(const float4*)&ea1[dg * 4];
    const float4 w04 = *(const float4*)&w2a[dg * 4];
    const float4 w14 = *(const float4*)&w2b[dg * 4];

    float r;
    r = __builtin_amdgcn_rcpf(fmaf(av0.x, b4.x, 1.f));
    s00[0] = fmaf(w04.x, r, s00[0]); s01[0] = fmaf(w14.x, r, s01[0]);
    r = __builtin_amdgcn_rcpf(fmaf(av1.x, b4.x, 1.f));
    s10[0] = fmaf(w04.x, r, s10[0]); s11[0] = fmaf(w14.x, r, s11[0]);

    r = __builtin_amdgcn_rcpf(fmaf(av0.y, b4.y, 1.f));
    s00[1] = fmaf(w04.y, r, s00[1]); s01[1] = fmaf(w14.y, r, s01[1]);
    r = __builtin_amdgcn_rcpf(fmaf(av1.y, b4.y, 1.f));
    s10[1] = fmaf(w04.y, r, s10[1]); s11[1] = fmaf(w14.y, r, s11[1]);

    r = __builtin_amdgcn_rcpf(fmaf(av0.z, b4.z, 1.f));
    s00[2] = fmaf(w04.z, r, s00[2]); s01[2] = fmaf(w14.z, r, s01[2]);
    r = __builtin_amdgcn_rcpf(fmaf(av1.z, b4.z, 1.f));
    s10[2] = fmaf(w04.z, r, s10[2]); s11[2] = fmaf(w14.z, r, s11[2]);

    r = __builtin_amdgcn_rcpf(fmaf(av0.w, b4.w, 1.f));
    s00[3] = fmaf(w04.w, r, s00[3]); s01[3] = fmaf(w14.w, r, s01[3]);
    r = __builtin_amdgcn_rcpf(fmaf(av1.w, b4.w, 1.f));
    s10[3] = fmaf(w04.w, r, s10[3]); s11[3] = fmaf(w14.w, r, s11[3]);
  }

  const float S00 = (s00[0] + s00[1]) + (s00[2] + s00[3]);
  const float S01 = (s01[0] + s01[1]) + (s01[2] + s01[3]);
  const float S10 = (s10[0] + s10[1]) + (s10[2] + s10[3]);
  const float S11 = (s11[0] + s11[1]) + (s11[2] + s11[3]);
  const float p00 = fmaf(-2.f, S00, sw0);
  const float p01 = fmaf(-2.f, S01, sw1);
  const float p10 = fmaf(-2.f, S10, sw0);
  const float p11 = fmaf(-2.f, S11, sw1);

  if (h2) {
    part[rp][0][lane][0] = p00; part[rp][0][lane][1] = p01;
    part[rp][1][lane][0] = p10; part[rp][1][lane][1] = p11;
  }
  __syncthreads();
  if (!h2) {
    float2 r0, r1;
    r0.x = p00 + part[rp][0][lane][0] + b2[0];
    r0.y = p01 + part[rp][0][lane][1] + b2[1];
    r1.x = p10 + part[rp][1][lane][0] + b2[0];
    r1.y = p11 + part[rp][1][lane][1] + b2[1];
    *(float2*)&out[((size_t)ia * NROWS + j) * 2] = r0;
    *(float2*)&out[((size_t)(ia + 1) * NROWS + j) * 2] = r1;
  }
}

// ---------------------------------------------------------------------------
extern "C" void kernel_launch(void* const* d_in, const int* in_sizes, int n_in,
                              void* d_out, int out_size, void* d_ws, size_t ws_size,
                              hipStream_t stream) {
  const float* p  = (const float*)d_in[0];   // [384, 768]
  const float* W1 = (const float*)d_in[1];   // [768, 1536]
  const float* b1 = (const float*)d_in[2];   // [768]
  const float* W2 = (const float*)d_in[3];   // [2, 768]
  const float* b2 = (const float*)d_in[4];   // [2]
  float* out = (float*)d_out;                // [384, 384, 2]
  float* ws  = (float*)d_ws;                 // ~5.3 MB used

  k0_cvt<<<dim3(720), 256, 0, stream>>>(p, W1, ws);

  dim3 g1(NCOL / 32, NROWS / 16);            // 48 x 24 = 1152 blocks
  k1_mfma<<<g1, 256, 0, stream>>>(b1, ws);

  dim3 g2(NROWS / 4, NROWS / 64);            // 96 x 6 = 576 blocks
  k2_fused<<<g2, 256, 0, stream>>>(ws, W2, b2, out);
}

// Round 3
// 97.972 us; speedup vs baseline: 1.0749x; 1.0749x over previous
//
#include <hip/hip_runtime.h>
#include <stdint.h>

#define NROWS 384
#define DDIM  768
#define NCOL  1536
#define L2E2  2.885390081777927f   // 2*log2(e): exp(2s) = exp2(L2E2*s)

// ws regions (float-slot offsets):
//   EA   [384 i][768 d]  fp32 at 0        (exp2(L2E2*(A+b1)), row-major)
//   EBt  [192 dg][384 j][4] fp32 at 294912 (exp2(L2E2*B), d-blocked)
//   pbf  [384 i][768 k]  bf16 at 589824   (p converted once)
//   wbf  [768 o][1536 c] bf16 at 737280   (W1 converted once)
#define WS_BT  294912
#define WS_PBF 589824
#define WS_WBF 737280

typedef short bf16x8 __attribute__((ext_vector_type(8)));
typedef float f32x4  __attribute__((ext_vector_type(4)));
typedef float f32x2  __attribute__((ext_vector_type(2)));

__device__ __forceinline__ uint16_t f2bf(float x) {  // RNE float->bf16
  const uint32_t u = __float_as_uint(x);
  return (uint16_t)((u + 0x7FFFu + ((u >> 16) & 1u)) >> 16);
}
__device__ __forceinline__ bf16x8 pack8(const float* f) {
  bf16x8 r;
  #pragma unroll
  for (int j = 0; j < 8; ++j) r[j] = (short)f2bf(f[j]);
  return r;
}

// ---------------------------------------------------------------------------
// K0: one-time fp32->bf16 conversion of p and W1 (layouts preserved).
// ---------------------------------------------------------------------------
__global__ __launch_bounds__(256) void k0_cvt(
    const float* __restrict__ p, const float* __restrict__ W1,
    float* __restrict__ ws) {
  const int t = blockIdx.x * 256 + threadIdx.x;
  const int NP = NROWS * DDIM / 8;          // 36864 p-tasks
  float f[8];
  if (t < NP) {
    *(float4*)&f[0] = *(const float4*)&p[t * 8];
    *(float4*)&f[4] = *(const float4*)&p[t * 8 + 4];
    *(bf16x8*)((uint16_t*)(ws + WS_PBF) + (size_t)t * 8) = pack8(f);
  } else {
    const int u = t - NP;                   // 147456 W1-tasks
    *(float4*)&f[0] = *(const float4*)&W1[(size_t)u * 8];
    *(float4*)&f[4] = *(const float4*)&W1[(size_t)u * 8 + 4];
    *(bf16x8*)((uint16_t*)(ws + WS_WBF) + (size_t)u * 8) = pack8(f);
  }
}

// ---------------------------------------------------------------------------
// K1: C[i][o] = sum_k p[i][k] * W1[o%768][(o>=768)*768 + k], MFMA bf16.
// bf16 fragments loaded directly (16B, L2-resident) — no pack VALU.
// Block = 256 thr = 4 waves = 2 n-subtiles x 2 k-halves (LDS combine).
// Grid 48x24 = 1152 blocks. Epilogue folds b1 + L2E2 AND the exp2:
// stores EA = exp2(L2E2*(A+b1)) row-major, EB = exp2(L2E2*B) d-blocked,
// so K2's inner loop needs no transcendental exp (exp(2s)=EA*EB).
// ---------------------------------------------------------------------------
__global__ __launch_bounds__(256) void k1_mfma(
    const float* __restrict__ b1, float* __restrict__ ws) {
  __shared__ float cmb[2][64][4];

  const int lane = threadIdx.x & 63;
  const int w    = threadIdx.x >> 6;
  const int nsub = w & 1;
  const int ksub = w >> 1;
  const int nn   = lane & 15;
  const int quad = lane >> 4;

  const int mbase = blockIdx.y * 16;
  const int nbase = blockIdx.x * 32 + nsub * 16;   // [0,1536)
  const int g     = nbase >= DDIM;
  const int obase = nbase - g * DDIM;              // W1 row base [0,768)

  const uint16_t* __restrict__ pa =
      (const uint16_t*)(ws + WS_PBF) + (size_t)(mbase + nn) * DDIM + ksub * 384 + quad * 8;
  const uint16_t* __restrict__ pb =
      (const uint16_t*)(ws + WS_WBF) + (size_t)(obase + nn) * NCOL + g * DDIM + ksub * 384 + quad * 8;

  f32x4 acc = {0.f, 0.f, 0.f, 0.f};

  #pragma unroll 4
  for (int kk = 0; kk < 384; kk += 32) {
    const bf16x8 a = *(const bf16x8*)&pa[kk];
    const bf16x8 b = *(const bf16x8*)&pb[kk];
    acc = __builtin_amdgcn_mfma_f32_16x16x32_bf16(a, b, acc, 0, 0, 0);
  }

  if (ksub == 1)
    *(float4*)&cmb[nsub][lane][0] = make_float4(acc[0], acc[1], acc[2], acc[3]);
  __syncthreads();
  if (ksub == 0) {
    const float4 o4 = *(const float4*)&cmb[nsub][lane][0];
    float v[4] = {acc[0] + o4.x, acc[1] + o4.y, acc[2] + o4.z, acc[3] + o4.w};
    const int od = obase + nn;
    if (!g) {
      const float bias = b1[od];
      float* __restrict__ A2 = ws;
      #pragma unroll
      for (int r = 0; r < 4; ++r)
        A2[(size_t)(mbase + quad * 4 + r) * DDIM + od] =
            __builtin_amdgcn_exp2f((v[r] + bias) * L2E2);
    } else {
      float* __restrict__ Bt = ws + WS_BT;
      const int hi = (od >> 2) * NROWS;
      const int lo = od & 3;
      #pragma unroll
      for (int r = 0; r < 4; ++r)
        Bt[(size_t)(hi + mbase + quad * 4 + r) * 4 + lo] =
            __builtin_amdgcn_exp2f(v[r] * L2E2);
    }
  }
}

// ---------------------------------------------------------------------------
// K2: logits[i][j][c] = (sumW_c - 2*sum_d W2[c][d]*r_ijd) + b2[c],
//     r = rcp(EA[i][d]*EB[j][d] + 1)   (exponentials precomputed in K1:
//     exp(2s) = EA*EB — no transcendental exp in the hot loop, only rcp).
// Structure = round-1 (REVERTED from 4-row tiling: 2.25 blocks/CU starved
// latency hiding, +3.4us). Block = 256 thr = 4 waves (d-quarters) x
// [2 i-rows x 64 j]. Grid (192,6) = 1152 blocks -> 18 waves/CU.
// EA/W2 wave-uniform scalar (SMEM) streams; EB coalesced per-lane float4.
// CHANGE this round: packed fp32 math. All inner-loop FMA pairs are
// naturally adjacent (EA d-pairs, b4 halves, W2 d-pairs, rcp-result
// pairs), so f32x2 ext-vector arithmetic (-ffp-contract=fast) lowers to
// v_pk_fma_f32: 24 scalar fma -> 12 pk_fma per dg. Issue/dg ~80 -> ~58 cy.
// ---------------------------------------------------------------------------
__global__ __launch_bounds__(256) void k2_fused(
    const float* __restrict__ ws, const float* __restrict__ W2,
    const float* __restrict__ b2, float* __restrict__ out) {
  __shared__ float part[3][2][64][2];

  const int lane = threadIdx.x & 63;
  const int h    = __builtin_amdgcn_readfirstlane(threadIdx.x >> 6);  // d-quarter
  const int i0   = blockIdx.x * 2;
  const int j    = blockIdx.y * 64 + lane;

  // Wave-uniform scalar streams for this d-quarter.
  const float* __restrict__ ea0 = ws + (size_t)i0 * DDIM + h * 192;
  const float* __restrict__ ea1 = ea0 + DDIM;
  const float* __restrict__ w2a = W2 + h * 192;
  const float* __restrict__ w2b = w2a + DDIM;

  // quarter-range sumW (wave-uniform after butterfly)
  float sw0 = w2a[lane] + w2a[lane + 64] + w2a[lane + 128];
  float sw1 = w2b[lane] + w2b[lane + 64] + w2b[lane + 128];
  #pragma unroll
  for (int off = 32; off; off >>= 1) {
    sw0 += __shfl_xor(sw0, off);
    sw1 += __shfl_xor(sw1, off);
  }

  const f32x4* __restrict__ B4 =
      (const f32x4*)(ws + WS_BT) + (size_t)(h * 48) * NROWS + j;

  const f32x2 one2 = {1.f, 1.f};
  // acc[row][class][d-half], each f32x2 over adjacent d elements
  f32x2 a00l = {0,0}, a00h = {0,0}, a01l = {0,0}, a01h = {0,0};
  f32x2 a10l = {0,0}, a10h = {0,0}, a11l = {0,0}, a11h = {0,0};

  #pragma unroll 4
  for (int dg = 0; dg < 48; ++dg) {
    const f32x4 b4  = B4[(size_t)dg * NROWS];           // coalesced per-lane (EB)
    const f32x2 blo = b4.xy, bhi = b4.zw;               // adjacent-VGPR pairs
    const f32x2 a0l = *(const f32x2*)&ea0[dg * 4];      // wave-uniform (SMEM)
    const f32x2 a0h = *(const f32x2*)&ea0[dg * 4 + 2];
    const f32x2 a1l = *(const f32x2*)&ea1[dg * 4];
    const f32x2 a1h = *(const f32x2*)&ea1[dg * 4 + 2];
    const f32x2 w0l = *(const f32x2*)&w2a[dg * 4];
    const f32x2 w0h = *(const f32x2*)&w2a[dg * 4 + 2];
    const f32x2 w1l = *(const f32x2*)&w2b[dg * 4];
    const f32x2 w1h = *(const f32x2*)&w2b[dg * 4 + 2];

    f32x2 t, r;
    t = a0l * blo + one2;                                // v_pk_fma_f32
    r[0] = __builtin_amdgcn_rcpf(t[0]);
    r[1] = __builtin_amdgcn_rcpf(t[1]);
    a00l = w0l * r + a00l;  a01l = w1l * r + a01l;       // v_pk_fma_f32

    t = a0h * bhi + one2;
    r[0] = __builtin_amdgcn_rcpf(t[0]);
    r[1] = __builtin_amdgcn_rcpf(t[1]);
    a00h = w0h * r + a00h;  a01h = w1h * r + a01h;

    t = a1l * blo + one2;
    r[0] = __builtin_amdgcn_rcpf(t[0]);
    r[1] = __builtin_amdgcn_rcpf(t[1]);
    a10l = w0l * r + a10l;  a11l = w1l * r + a11l;

    t = a1h * bhi + one2;
    r[0] = __builtin_amdgcn_rcpf(t[0]);
    r[1] = __builtin_amdgcn_rcpf(t[1]);
    a10h = w0h * r + a10h;  a11h = w1h * r + a11h;
  }

  const float S00 = (a00l[0] + a00l[1]) + (a00h[0] + a00h[1]);
  const float S01 = (a01l[0] + a01l[1]) + (a01h[0] + a01h[1]);
  const float S10 = (a10l[0] + a10l[1]) + (a10h[0] + a10h[1]);
  const float S11 = (a11l[0] + a11l[1]) + (a11h[0] + a11h[1]);
  const float p00 = fmaf(-2.f, S00, sw0);
  const float p01 = fmaf(-2.f, S01, sw1);
  const float p10 = fmaf(-2.f, S10, sw0);
  const float p11 = fmaf(-2.f, S11, sw1);

  if (h) {
    part[h - 1][0][lane][0] = p00; part[h - 1][0][lane][1] = p01;
    part[h - 1][1][lane][0] = p10; part[h - 1][1][lane][1] = p11;
  }
  __syncthreads();
  if (!h) {
    float2 r0, r1;
    r0.x = p00 + part[0][0][lane][0] + part[1][0][lane][0] + part[2][0][lane][0] + b2[0];
    r0.y = p01 + part[0][0][lane][1] + part[1][0][lane][1] + part[2][0][lane][1] + b2[1];
    r1.x = p10 + part[0][1][lane][0] + part[1][1][lane][0] + part[2][1][lane][0] + b2[0];
    r1.y = p11 + part[0][1][lane][1] + part[1][1][lane][1] + part[2][1][lane][1] + b2[1];
    *(float2*)&out[((size_t)i0 * NROWS + j) * 2] = r0;
    *(float2*)&out[((size_t)(i0 + 1) * NROWS + j) * 2] = r1;
  }
}

// ---------------------------------------------------------------------------
extern "C" void kernel_launch(void* const* d_in, const int* in_sizes, int n_in,
                              void* d_out, int out_size, void* d_ws, size_t ws_size,
                              hipStream_t stream) {
  const float* p  = (const float*)d_in[0];   // [384, 768]
  const float* W1 = (const float*)d_in[1];   // [768, 1536]
  const float* b1 = (const float*)d_in[2];   // [768]
  const float* W2 = (const float*)d_in[3];   // [2, 768]
  const float* b2 = (const float*)d_in[4];   // [2]
  float* out = (float*)d_out;                // [384, 384, 2]
  float* ws  = (float*)d_ws;                 // ~5.3 MB used

  k0_cvt<<<dim3(720), 256, 0, stream>>>(p, W1, ws);

  dim3 g1(NCOL / 32, NROWS / 16);            // 48 x 24 = 1152 blocks
  k1_mfma<<<g1, 256, 0, stream>>>(b1, ws);

  dim3 g2(NROWS / 2, NROWS / 64);            // 192 x 6 = 1152 blocks
  k2_fused<<<g2, 256, 0, stream>>>(ws, W2, b2, out);
}